// Round 1
// baseline (827.927 us; speedup 1.0000x reference)
//
#include <hip/hip_runtime.h>

typedef __bf16 bf16;
typedef __bf16 bf16x8 __attribute__((ext_vector_type(8)));
typedef float f32x4 __attribute__((ext_vector_type(4)));

#define AS1(p) ((const __attribute__((address_space(1))) void*)(p))
#define AS3(p) ((__attribute__((address_space(3))) void*)(p))

// ---------------- pack & window-permute x (fp32) -> win (bf16) ----------------
// x: (B=2, 16384, 1280) -> win: (128 windows * 256 tokens, 1280)
__global__ void k_pack_win(const float* __restrict__ x, bf16* __restrict__ win) {
  int idx = blockIdx.x * 256 + threadIdx.x;  // one thread = 8 elems
  int r = idx / 160;                         // window-token row (1280/8 = 160)
  int c8 = idx - r * 160;
  int w = r >> 8, n = r & 255;
  int b = w >> 6, hb = (w >> 3) & 7, wb = w & 7;
  int t = n >> 6, i = (n >> 3) & 7, j = n & 7;
  size_t srow = (size_t)((b * 4 + t) * 4096 + (hb * 8 + i) * 64 + wb * 8 + j);
  const float4* s = (const float4*)(x + srow * 1280 + c8 * 8);
  float4 f0 = s[0], f1 = s[1];
  bf16x8 o;
  o[0] = (bf16)f0.x; o[1] = (bf16)f0.y; o[2] = (bf16)f0.z; o[3] = (bf16)f0.w;
  o[4] = (bf16)f1.x; o[5] = (bf16)f1.y; o[6] = (bf16)f1.z; o[7] = (bf16)f1.w;
  *(bf16x8*)(win + (size_t)idx * 8) = o;
}

// ---------------- transpose + convert weights: (K,N) f32 -> (N,K) bf16 ----------------
__global__ void k_transpose_w(const float* __restrict__ w, bf16* __restrict__ wt,
                              int K, int N) {
  __shared__ float tile[32][33];
  int tx = threadIdx.x & 31, ty = threadIdx.x >> 5;
  int c0 = blockIdx.x * 32, r0 = blockIdx.y * 32;
#pragma unroll
  for (int yy = ty; yy < 32; yy += 8)
    tile[yy][tx] = w[(size_t)(r0 + yy) * N + c0 + tx];
  __syncthreads();
#pragma unroll
  for (int yy = ty; yy < 32; yy += 8)
    wt[(size_t)(c0 + yy) * K + r0 + tx] = (bf16)tile[tx][yy];
}

// ---------------- MRoPE cos/sin table: [n=256][c=64] interleaved (cos,sin) ----------------
__global__ void k_rope_table(float* __restrict__ tab) {
  int idx = blockIdx.x * 256 + threadIdx.x;  // 16384
  int n = idx >> 6, c = idx & 63;
  int t = n >> 6, i = (n >> 3) & 7, j = n & 7;
  float pos = (c < 16) ? (float)t : ((c < 40) ? (float)i : (float)j);
  float inv = powf(10000.f, -(float)c * (1.f / 64.f));
  float a = pos * inv;
  tab[idx * 2] = cosf(a);
  tab[idx * 2 + 1] = sinf(a);
}

// ---------------- RoPE apply (in-place on qkv bf16) + q scale ----------------
__global__ void k_rope_apply(bf16* __restrict__ qkv, const float* __restrict__ tab) {
  int idx = blockIdx.x * 256 + threadIdx.x;  // 32768*10*64
  int c = idx & 63;
  int gh = idx >> 6;
  int gr = gh / 10;
  int h = gh - gr * 10;
  int n = gr & 255;
  float cs = tab[(n * 64 + c) * 2], sn = tab[(n * 64 + c) * 2 + 1];
  size_t base = (size_t)gr * 3840 + h * 128;
  const float scale = 0.08838834764831845f;  // 128^-0.5
  float q1 = (float)qkv[base + c], q2 = (float)qkv[base + 64 + c];
  qkv[base + c]      = (bf16)((q1 * cs - q2 * sn) * scale);
  qkv[base + 64 + c] = (bf16)((q2 * cs + q1 * sn) * scale);
  float k1 = (float)qkv[base + 1280 + c], k2 = (float)qkv[base + 1344 + c];
  qkv[base + 1280 + c] = (bf16)(k1 * cs - k2 * sn);
  qkv[base + 1344 + c] = (bf16)(k2 * cs + k1 * sn);
}

// ---------------- GEMM: C = A(M,1280; row stride lda) * Bt(N,1280)^T + bias ----------------
// EPI 0: write bf16 to Cout (stride ldc).  EPI 1: write f32 to Cout with reverse
// window permutation of rows (stride ldc).
template <int EPI>
__global__ __launch_bounds__(256, 2) void k_gemm(
    const bf16* __restrict__ A, int lda, const bf16* __restrict__ Bt,
    const float* __restrict__ bias, void* __restrict__ Cout, int ldc) {
  __shared__ bf16 As[128 * 64];
  __shared__ bf16 Bs[128 * 64];
  const int tid = threadIdx.x, lane = tid & 63, wv = tid >> 6;
  const int m0 = blockIdx.x * 128, n0 = blockIdx.y * 128;
  const int wr = (wv >> 1) * 64, wc = (wv & 1) * 64;
  const int l8 = lane >> 3, l7 = lane & 7, lq = lane >> 4, lr = lane & 15;

  f32x4 acc[4][4];
#pragma unroll
  for (int a = 0; a < 4; ++a)
#pragma unroll
    for (int b = 0; b < 4; ++b) acc[a][b] = (f32x4){0.f, 0.f, 0.f, 0.f};

  const bf16* Ab = A + (size_t)m0 * lda;
  const bf16* Bb = Bt + (size_t)n0 * 1280;

  for (int kt = 0; kt < 20; ++kt) {
#pragma unroll
    for (int i2 = 0; i2 < 4; ++i2) {
      int chunk = i2 * 4 + wv;  // 16 chunks of 1KB (8 rows x 128B)
      __builtin_amdgcn_global_load_lds(
          AS1(Ab + (size_t)(chunk * 8 + l8) * lda + kt * 64 + l7 * 8),
          AS3(As + chunk * 512), 16, 0, 0);
      __builtin_amdgcn_global_load_lds(
          AS1(Bb + (size_t)(chunk * 8 + l8) * 1280 + kt * 64 + l7 * 8),
          AS3(Bs + chunk * 512), 16, 0, 0);
    }
    __syncthreads();
#pragma unroll
    for (int kb = 0; kb < 2; ++kb) {
      bf16x8 af[4], bfv[4];
#pragma unroll
      for (int mt = 0; mt < 4; ++mt)
        af[mt] = *(const bf16x8*)(As + (wr + mt * 16 + lr) * 64 + kb * 32 + lq * 8);
#pragma unroll
      for (int nt = 0; nt < 4; ++nt)
        bfv[nt] = *(const bf16x8*)(Bs + (wc + nt * 16 + lr) * 64 + kb * 32 + lq * 8);
#pragma unroll
      for (int mt = 0; mt < 4; ++mt)
#pragma unroll
        for (int nt = 0; nt < 4; ++nt)
          acc[mt][nt] = __builtin_amdgcn_mfma_f32_16x16x32_bf16(af[mt], bfv[nt],
                                                                acc[mt][nt], 0, 0, 0);
    }
    __syncthreads();
  }

#pragma unroll
  for (int nt = 0; nt < 4; ++nt) {
    int col = n0 + wc + nt * 16 + lr;
    float bv = bias[col];
#pragma unroll
    for (int mt = 0; mt < 4; ++mt) {
#pragma unroll
      for (int r = 0; r < 4; ++r) {
        int row = m0 + wr + mt * 16 + lq * 4 + r;
        float v = acc[mt][nt][r] + bv;
        if constexpr (EPI == 0) {
          ((bf16*)Cout)[(size_t)row * ldc + col] = (bf16)v;
        } else {
          int w = row >> 8, n = row & 255;
          int b = w >> 6, hb = (w >> 3) & 7, wb = w & 7;
          int t = n >> 6, i = (n >> 3) & 7, j = n & 7;
          size_t orow = (size_t)((b * 4 + t) * 4096 + (hb * 8 + i) * 64 + wb * 8 + j);
          ((float*)Cout)[orow * ldc + col] = v;
        }
      }
    }
  }
}

// ---------------- attention: one block per (window, head); 8 waves x 32 Q rows ----------------
// Reads q/k/v from qkv (stride 3840); writes O into the q-section in place
// (each block touches only its own rows x [h*128, h*128+128) columns).
__global__ __launch_bounds__(512) void k_attn(bf16* __restrict__ qkv) {
  int wh = blockIdx.x;
  int win = wh / 10, h = wh - win * 10;
  bf16* base = qkv + (size_t)win * 256 * 3840 + h * 128;
  const int tid = threadIdx.x, lane = tid & 63, wv = tid >> 6;
  const int lq = lane >> 4, lr = lane & 15;
  const int qrow0 = wv * 32;

  __shared__ bf16 Kl[64 * 136];    // [tok][d], row pad +8 -> 2-way-free ds_read_b128
  __shared__ bf16 Vt[128 * 72];    // [d][tok], row pad +8
  __shared__ bf16 Pl[8][16 * 72];  // per-wave P strip (one m-tile at a time)

  bf16x8 qf[2][4];
#pragma unroll
  for (int mt = 0; mt < 2; ++mt)
#pragma unroll
    for (int kq = 0; kq < 4; ++kq)
      qf[mt][kq] = *(const bf16x8*)(base + (size_t)(qrow0 + mt * 16 + lr) * 3840 +
                                    kq * 32 + lq * 8);

  float mrun[2][4], lrun[2][4];
  f32x4 oacc[2][8];
#pragma unroll
  for (int mt = 0; mt < 2; ++mt)
#pragma unroll
    for (int r = 0; r < 4; ++r) { mrun[mt][r] = -1e30f; lrun[mt][r] = 0.f; }
#pragma unroll
  for (int mt = 0; mt < 2; ++mt)
#pragma unroll
    for (int dt = 0; dt < 8; ++dt) oacc[mt][dt] = (f32x4){0.f, 0.f, 0.f, 0.f};

  for (int kb_t = 0; kb_t < 4; ++kb_t) {
    __syncthreads();
    // stage K block [64][128] and V^T block [128][64]
#pragma unroll
    for (int p = 0; p < 2; ++p) {
      int item = p * 512 + tid;           // 1024 items = 64 rows x 16 chunks
      int rr = item >> 4, cc = item & 15;
      bf16x8 kv = *(const bf16x8*)(base + 1280 + (size_t)(kb_t * 64 + rr) * 3840 + cc * 8);
      *(bf16x8*)(Kl + rr * 136 + cc * 8) = kv;
      bf16x8 vv = *(const bf16x8*)(base + 2560 + (size_t)(kb_t * 64 + rr) * 3840 + cc * 8);
#pragma unroll
      for (int ee = 0; ee < 8; ++ee) {
        int e = (ee + cc) & 7;  // rotate -> spread banks on scatter writes
        Vt[(cc * 8 + e) * 72 + rr] = vv[e];
      }
    }
    __syncthreads();

    // S = Q K^T  (D-layout: col = token = lr, row = lq*4 + r)
    f32x4 s[2][4];
#pragma unroll
    for (int mt = 0; mt < 2; ++mt)
#pragma unroll
      for (int nt = 0; nt < 4; ++nt) s[mt][nt] = (f32x4){0.f, 0.f, 0.f, 0.f};
#pragma unroll
    for (int nt = 0; nt < 4; ++nt) {
      bf16x8 kf[4];
#pragma unroll
      for (int kq = 0; kq < 4; ++kq)
        kf[kq] = *(const bf16x8*)(Kl + (nt * 16 + lr) * 136 + kq * 32 + lq * 8);
#pragma unroll
      for (int kq = 0; kq < 4; ++kq) {
        s[0][nt] = __builtin_amdgcn_mfma_f32_16x16x32_bf16(qf[0][kq], kf[kq], s[0][nt], 0, 0, 0);
        s[1][nt] = __builtin_amdgcn_mfma_f32_16x16x32_bf16(qf[1][kq], kf[kq], s[1][nt], 0, 0, 0);
      }
    }

#pragma unroll
    for (int mt = 0; mt < 2; ++mt) {
#pragma unroll
      for (int r = 0; r < 4; ++r) {
        float mx = fmaxf(fmaxf(s[mt][0][r], s[mt][1][r]), fmaxf(s[mt][2][r], s[mt][3][r]));
        mx = fmaxf(mx, __shfl_xor(mx, 1));
        mx = fmaxf(mx, __shfl_xor(mx, 2));
        mx = fmaxf(mx, __shfl_xor(mx, 4));
        mx = fmaxf(mx, __shfl_xor(mx, 8));
        float mold = mrun[mt][r];
        float mnew = fmaxf(mold, mx);
        float corr = __expf(mold - mnew);
        mrun[mt][r] = mnew;
        float rs = 0.f;
#pragma unroll
        for (int nt = 0; nt < 4; ++nt) {
          float p = __expf(s[mt][nt][r] - mnew);
          s[mt][nt][r] = p;
          rs += p;
        }
        rs += __shfl_xor(rs, 1);
        rs += __shfl_xor(rs, 2);
        rs += __shfl_xor(rs, 4);
        rs += __shfl_xor(rs, 8);
        lrun[mt][r] = lrun[mt][r] * corr + rs;
#pragma unroll
        for (int dt = 0; dt < 8; ++dt) oacc[mt][dt][r] *= corr;
#pragma unroll
        for (int nt = 0; nt < 4; ++nt)
          Pl[wv][(lq * 4 + r) * 72 + nt * 16 + lr] = (bf16)s[mt][nt][r];
      }
      asm volatile("s_waitcnt lgkmcnt(0)" ::: "memory");
#pragma unroll
      for (int kq = 0; kq < 2; ++kq) {
        bf16x8 pf = *(const bf16x8*)(Pl[wv] + lr * 72 + kq * 32 + lq * 8);
#pragma unroll
        for (int dt = 0; dt < 8; ++dt) {
          bf16x8 vf = *(const bf16x8*)(Vt + (dt * 16 + lr) * 72 + kq * 32 + lq * 8);
          oacc[mt][dt] = __builtin_amdgcn_mfma_f32_16x16x32_bf16(pf, vf, oacc[mt][dt], 0, 0, 0);
        }
      }
    }
  }

  // O /= l ; write into q-section (stride 3840), cols h*128 + [0,128)
#pragma unroll
  for (int mt = 0; mt < 2; ++mt) {
#pragma unroll
    for (int r = 0; r < 4; ++r) {
      float inv = 1.f / lrun[mt][r];
#pragma unroll
      for (int dt = 0; dt < 8; ++dt) {
        int trow = qrow0 + mt * 16 + lq * 4 + r;
        base[(size_t)trow * 3840 + dt * 16 + lr] = (bf16)(oacc[mt][dt][r] * inv);
      }
    }
  }
}

extern "C" void kernel_launch(void* const* d_in, const int* in_sizes, int n_in,
                              void* d_out, int out_size, void* d_ws, size_t ws_size,
                              hipStream_t stream) {
  const float* x      = (const float*)d_in[0];
  const float* w_qkv  = (const float*)d_in[1];
  const float* b_qkv  = (const float*)d_in[2];
  const float* w_proj = (const float*)d_in[3];
  const float* b_proj = (const float*)d_in[4];

  // Transient buffers live in d_out (dead before final GEMM rewrites it):
  //   win   [0, 83886080)      : 32768x1280 bf16
  //   wqkvT [83886080, +9830400): 3840x1280 bf16
  //   tab   [93716480, +131072) : 256x64x2 f32
  char* outc = (char*)d_out;
  bf16* win    = (bf16*)outc;
  bf16* wqkvT  = (bf16*)(outc + 83886080);
  float* tab   = (float*)(outc + 83886080 + 9830400);
  // Workspace: qkv 32768x3840 bf16 (251,658,240 B) + wprojT 1280x1280 bf16
  char* wsc = (char*)d_ws;
  bf16* qkv    = (bf16*)wsc;
  bf16* wprojT = (bf16*)(wsc + 251658240);

  k_pack_win<<<20480, 256, 0, stream>>>(x, win);
  k_transpose_w<<<dim3(120, 40), 256, 0, stream>>>(w_qkv, wqkvT, 1280, 3840);
  k_transpose_w<<<dim3(40, 40), 256, 0, stream>>>(w_proj, wprojT, 1280, 1280);
  k_rope_table<<<64, 256, 0, stream>>>(tab);
  k_gemm<0><<<dim3(256, 30), 256, 0, stream>>>(win, 1280, wqkvT, b_qkv, (void*)qkv, 3840);
  k_rope_apply<<<81920, 256, 0, stream>>>(qkv, tab);
  k_attn<<<1280, 512, 0, stream>>>(qkv);  // writes O over q-section
  k_gemm<1><<<dim3(256, 10), 256, 0, stream>>>(qkv, 3840, wprojT, b_proj, d_out, 1280);
}

// Round 3
// 827.437 us; speedup vs baseline: 1.0006x; 1.0006x over previous
//
#include <hip/hip_runtime.h>

typedef __bf16 bf16;
typedef __bf16 bf16x8 __attribute__((ext_vector_type(8)));
typedef float f32x4 __attribute__((ext_vector_type(4)));

#define AS1(p) ((const __attribute__((address_space(1))) void*)(p))
#define AS3(p) ((__attribute__((address_space(3))) void*)(p))

// ---------------- pack & window-permute x (fp32) -> win (bf16) ----------------
__global__ void k_pack_win(const float* __restrict__ x, bf16* __restrict__ win) {
  int idx = blockIdx.x * 256 + threadIdx.x;  // one thread = 8 elems
  int r = idx / 160;
  int c8 = idx - r * 160;
  int w = r >> 8, n = r & 255;
  int b = w >> 6, hb = (w >> 3) & 7, wb = w & 7;
  int t = n >> 6, i = (n >> 3) & 7, j = n & 7;
  size_t srow = (size_t)((b * 4 + t) * 4096 + (hb * 8 + i) * 64 + wb * 8 + j);
  const float4* s = (const float4*)(x + srow * 1280 + c8 * 8);
  float4 f0 = s[0], f1 = s[1];
  bf16x8 o;
  o[0] = (bf16)f0.x; o[1] = (bf16)f0.y; o[2] = (bf16)f0.z; o[3] = (bf16)f0.w;
  o[4] = (bf16)f1.x; o[5] = (bf16)f1.y; o[6] = (bf16)f1.z; o[7] = (bf16)f1.w;
  *(bf16x8*)(win + (size_t)idx * 8) = o;
}

// ---------------- transpose + convert weights: (K,N) f32 -> (N,K) bf16 ----------------
__global__ void k_transpose_w(const float* __restrict__ w, bf16* __restrict__ wt,
                              int K, int N) {
  __shared__ float tile[32][33];
  int tx = threadIdx.x & 31, ty = threadIdx.x >> 5;
  int c0 = blockIdx.x * 32, r0 = blockIdx.y * 32;
#pragma unroll
  for (int yy = ty; yy < 32; yy += 8)
    tile[yy][tx] = w[(size_t)(r0 + yy) * N + c0 + tx];
  __syncthreads();
#pragma unroll
  for (int yy = ty; yy < 32; yy += 8)
    wt[(size_t)(c0 + yy) * K + r0 + tx] = (bf16)tile[tx][yy];
}

// ---------------- MRoPE cos/sin table: [n=256][c=64] interleaved (cos,sin) ----------------
__global__ void k_rope_table(float* __restrict__ tab) {
  int idx = blockIdx.x * 256 + threadIdx.x;  // 16384
  int n = idx >> 6, c = idx & 63;
  int t = n >> 6, i = (n >> 3) & 7, j = n & 7;
  float pos = (c < 16) ? (float)t : ((c < 40) ? (float)i : (float)j);
  float inv = powf(10000.f, -(float)c * (1.f / 64.f));
  float a = pos * inv;
  tab[idx * 2] = cosf(a);
  tab[idx * 2 + 1] = sinf(a);
}

// ---------------- GEMM: 256x256 tile, BK=64, 8-wave, 4-phase counted-vmcnt ----------------
// C = A(M,1280; stride lda) * Bt(N,1280)^T + bias.
// EPI 0: bf16 out (stride ldc). EPI 1: f32 out with reverse-window row permute (NT store).
template <int EPI>
__global__ __launch_bounds__(512, 2) void k_gemm(
    const bf16* __restrict__ A, int lda, const bf16* __restrict__ Bt,
    const float* __restrict__ bias, void* __restrict__ Cout, int ldc) {
  __shared__ bf16 sA[2][16384];  // [buf][256 rows][64 k] swizzled
  __shared__ bf16 sB[2][16384];
  const int tid = threadIdx.x, lane = tid & 63, wv = tid >> 6;
  const int wm = wv >> 2, wn = wv & 3;         // 2M x 4N waves, 128x64 per wave
  const int lq = lane >> 4, lr = lane & 15;

  // XCD swizzle: block i runs on XCD i%8; give each XCD 16 contiguous m-blocks x all n.
  int wg_local = blockIdx.x >> 3;
  int xcd = blockIdx.x & 7;
  int n_blk = wg_local >> 4;
  int m_blk = (xcd << 4) + (wg_local & 15);
  const int m0 = m_blk * 256, n0 = n_blk * 256;

  const bf16* Ab = A + (size_t)m0 * lda;
  const bf16* Bb = Bt + (size_t)n0 * 1280;
  const int srow = tid >> 3;                // 0..63 staging row within 64-row round
  const int skg = (tid & 7) ^ (srow & 7);   // swizzled k-group (involution with read XOR)
  const int sldso = wv * 512;               // per-wave elems within an 8KB round

#define STAGE_A(bufidx, h, kt)                                                  \
  do {                                                                          \
    __builtin_amdgcn_global_load_lds(                                           \
        AS1(Ab + (size_t)((h)*128 + srow) * lda + (kt)*64 + skg * 8),           \
        AS3(&sA[bufidx][(h)*8192 + sldso]), 16, 0, 0);                          \
    __builtin_amdgcn_global_load_lds(                                           \
        AS1(Ab + (size_t)((h)*128 + 64 + srow) * lda + (kt)*64 + skg * 8),      \
        AS3(&sA[bufidx][(h)*8192 + 4096 + sldso]), 16, 0, 0);                   \
  } while (0)

#define STAGE_B(bufidx, h, kt)                                                  \
  do {                                                                          \
    __builtin_amdgcn_global_load_lds(                                           \
        AS1(Bb + (size_t)((h)*128 + srow) * 1280 + (kt)*64 + skg * 8),          \
        AS3(&sB[bufidx][(h)*8192 + sldso]), 16, 0, 0);                          \
    __builtin_amdgcn_global_load_lds(                                           \
        AS1(Bb + (size_t)((h)*128 + 64 + srow) * 1280 + (kt)*64 + skg * 8),     \
        AS3(&sB[bufidx][(h)*8192 + 4096 + sldso]), 16, 0, 0);                   \
  } while (0)

#define LOAD_A(mh)                                                              \
  _Pragma("unroll") for (int mt = 0; mt < 4; ++mt)                              \
  _Pragma("unroll") for (int kb = 0; kb < 2; ++kb) {                            \
    int row_ = wm * 128 + (mh)*64 + mt * 16 + lr;                               \
    int ksw_ = (kb * 32 + lq * 8) ^ ((lr & 7) << 3);                            \
    af[mt][kb] = *(const bf16x8*)&pA[row_ * 64 + ksw_];                         \
  }

#define LOAD_B(dst, nh)                                                         \
  _Pragma("unroll") for (int nt = 0; nt < 2; ++nt)                              \
  _Pragma("unroll") for (int kb = 0; kb < 2; ++kb) {                            \
    int row_ = wn * 64 + (nh)*32 + nt * 16 + lr;                                \
    int ksw_ = (kb * 32 + lq * 8) ^ ((lr & 7) << 3);                            \
    dst[nt][kb] = *(const bf16x8*)&pB[row_ * 64 + ksw_];                        \
  }

#define MFMA_Q(MH, NH, bvec)                                                    \
  _Pragma("unroll") for (int mt = 0; mt < 4; ++mt)                              \
  _Pragma("unroll") for (int nt = 0; nt < 2; ++nt)                              \
  _Pragma("unroll") for (int kb = 0; kb < 2; ++kb)                              \
    acc[(MH)*4 + mt][(NH)*2 + nt] = __builtin_amdgcn_mfma_f32_16x16x32_bf16(    \
        af[mt][kb], bvec[nt][kb], acc[(MH)*4 + mt][(NH)*2 + nt], 0, 0, 0);

  f32x4 acc[8][4];
#pragma unroll
  for (int i = 0; i < 8; ++i)
#pragma unroll
    for (int j = 0; j < 4; ++j) acc[i][j] = (f32x4){0.f, 0.f, 0.f, 0.f};

  // Prologue: tile0 A+B, tile1 B; keep tile1-B in flight past the wait.
  STAGE_A(0, 0, 0); STAGE_A(0, 1, 0);
  STAGE_B(0, 0, 0); STAGE_B(0, 1, 0);
  STAGE_B(1, 0, 1); STAGE_B(1, 1, 1);
  asm volatile("s_waitcnt vmcnt(4)" ::: "memory");
  __builtin_amdgcn_s_barrier();

  bf16x8 af[4][2], bfa[2][2], bfb[2][2];

#pragma unroll 2
  for (int t = 0; t < 20; ++t) {
    const int b = t & 1, bn = b ^ 1;
    const int ktA = (t + 1 < 20) ? t + 1 : 19;  // clamp: keeps vmcnt counts uniform
    const int ktB = (t + 2 < 20) ? t + 2 : 19;
    const bf16* pA = sA[b];
    const bf16* pB = sB[b];
    // phase 0: read A(mh0)+B(nh0); stage A-half0 of tile t+1
    LOAD_A(0);
    LOAD_B(bfa, 0);
    STAGE_A(bn, 0, ktA);
    __builtin_amdgcn_s_barrier();
    asm volatile("s_waitcnt lgkmcnt(0)" ::: "memory");
    __builtin_amdgcn_s_setprio(1);
    MFMA_Q(0, 0, bfa);
    __builtin_amdgcn_s_setprio(0);
    __builtin_amdgcn_s_barrier();
    // phase 1: read B(nh1); stage A-half1 of tile t+1
    LOAD_B(bfb, 1);
    STAGE_A(bn, 1, ktA);
    __builtin_amdgcn_s_barrier();
    asm volatile("s_waitcnt lgkmcnt(0)" ::: "memory");
    __builtin_amdgcn_s_setprio(1);
    MFMA_Q(0, 1, bfb);
    __builtin_amdgcn_s_setprio(0);
    __builtin_amdgcn_s_barrier();
    // phase 2: read A(mh1); stage B-half0 of tile t+2 (region retired after ph1)
    LOAD_A(1);
    STAGE_B(b, 0, ktB);
    __builtin_amdgcn_s_barrier();
    asm volatile("s_waitcnt lgkmcnt(0)" ::: "memory");
    __builtin_amdgcn_s_setprio(1);
    MFMA_Q(1, 0, bfa);
    __builtin_amdgcn_s_setprio(0);
    __builtin_amdgcn_s_barrier();
    // phase 3: stage B-half1 of tile t+2; counted vmcnt(4) then tile boundary
    STAGE_B(b, 1, ktB);
    __builtin_amdgcn_s_barrier();
    asm volatile("s_waitcnt lgkmcnt(0)" ::: "memory");
    __builtin_amdgcn_s_setprio(1);
    MFMA_Q(1, 1, bfb);
    __builtin_amdgcn_s_setprio(0);
    asm volatile("s_waitcnt vmcnt(4)" ::: "memory");
    __builtin_amdgcn_s_barrier();
  }

#pragma unroll
  for (int ni = 0; ni < 4; ++ni) {
    int col = n0 + wn * 64 + ni * 16 + lr;
    float bv = bias[col];
#pragma unroll
    for (int mi = 0; mi < 8; ++mi) {
#pragma unroll
      for (int r = 0; r < 4; ++r) {
        int row = m0 + wm * 128 + mi * 16 + lq * 4 + r;
        float v = acc[mi][ni][r] + bv;
        if constexpr (EPI == 0) {
          ((bf16*)Cout)[(size_t)row * ldc + col] = (bf16)v;
        } else {
          int w = row >> 8, n = row & 255;
          int b2 = w >> 6, hb = (w >> 3) & 7, wb = w & 7;
          int t2 = n >> 6, i2 = (n >> 3) & 7, j2 = n & 7;
          size_t orow = (size_t)((b2 * 4 + t2) * 4096 + (hb * 8 + i2) * 64 + wb * 8 + j2);
          __builtin_nontemporal_store(v, &((float*)Cout)[orow * ldc + col]);
        }
      }
    }
  }
#undef STAGE_A
#undef STAGE_B
#undef LOAD_A
#undef LOAD_B
#undef MFMA_Q
}

// ---------------- attention + fused MRoPE: one block per (window, head) ----------------
// Reads q/k/v from qkv (stride 3840), applies RoPE to Q (with 1/sqrt(d) scale) and K
// on the fly, writes O into the q-section in place.
__global__ __launch_bounds__(512) void k_attn(bf16* __restrict__ qkv,
                                              const float* __restrict__ tab) {
  int wh = blockIdx.x;
  int win = wh / 10, h = wh - win * 10;
  bf16* base = qkv + (size_t)win * 256 * 3840 + h * 128;
  const int tid = threadIdx.x, lane = tid & 63, wv = tid >> 6;
  const int lq = lane >> 4, lr = lane & 15;
  const int qrow0 = wv * 32;

  __shared__ bf16 Kl[64 * 136];    // [tok][d], pad +8
  __shared__ bf16 Vt[128 * 72];    // [d][tok], pad +8
  __shared__ bf16 Pl[8][16 * 72];  // per-wave P strip

  // Q fragments + in-register RoPE + scale
  bf16x8 qf[2][4];
#pragma unroll
  for (int mt = 0; mt < 2; ++mt) {
    int n = qrow0 + mt * 16 + lr;
#pragma unroll
    for (int kq = 0; kq < 4; ++kq)
      qf[mt][kq] = *(const bf16x8*)(base + (size_t)n * 3840 + kq * 32 + lq * 8);
    const float* tb = tab + (n * 64 + lq * 8) * 2;
#pragma unroll
    for (int kq = 0; kq < 2; ++kq)
#pragma unroll
      for (int e = 0; e < 8; ++e) {
        float cs = tb[(kq * 32 + e) * 2], sn = tb[(kq * 32 + e) * 2 + 1];
        float lo = (float)qf[mt][kq][e], hi = (float)qf[mt][kq + 2][e];
        qf[mt][kq][e] = (bf16)((lo * cs - hi * sn) * 0.08838834764831845f);
        qf[mt][kq + 2][e] = (bf16)((hi * cs + lo * sn) * 0.08838834764831845f);
      }
  }

  float mrun[2][4], lrun[2][4];
  f32x4 oacc[2][8];
#pragma unroll
  for (int mt = 0; mt < 2; ++mt)
#pragma unroll
    for (int r = 0; r < 4; ++r) { mrun[mt][r] = -1e30f; lrun[mt][r] = 0.f; }
#pragma unroll
  for (int mt = 0; mt < 2; ++mt)
#pragma unroll
    for (int dt = 0; dt < 8; ++dt) oacc[mt][dt] = (f32x4){0.f, 0.f, 0.f, 0.f};

  for (int kb_t = 0; kb_t < 4; ++kb_t) {
    __syncthreads();
    // stage K block [64][128] with fused RoPE: 512 items (row, col-pair)
    {
      int rr = tid >> 3, cp = tid & 7;
      const bf16* krow = base + 1280 + (size_t)(kb_t * 64 + rr) * 3840;
      bf16x8 klo = *(const bf16x8*)(krow + cp * 8);
      bf16x8 khi = *(const bf16x8*)(krow + cp * 8 + 64);
      const float* tb = tab + ((kb_t * 64 + rr) * 64 + cp * 8) * 2;
      bf16x8 olo, ohi;
#pragma unroll
      for (int e = 0; e < 8; ++e) {
        float cs = tb[e * 2], sn = tb[e * 2 + 1];
        float lo = (float)klo[e], hi = (float)khi[e];
        olo[e] = (bf16)(lo * cs - hi * sn);
        ohi[e] = (bf16)(hi * cs + lo * sn);
      }
      *(bf16x8*)(Kl + rr * 136 + cp * 8) = olo;
      *(bf16x8*)(Kl + rr * 136 + cp * 8 + 64) = ohi;
    }
    // stage V^T block [128][64]
#pragma unroll
    for (int p = 0; p < 2; ++p) {
      int item = p * 512 + tid;
      int rr = item >> 4, cc = item & 15;
      bf16x8 vv = *(const bf16x8*)(base + 2560 + (size_t)(kb_t * 64 + rr) * 3840 + cc * 8);
#pragma unroll
      for (int ee = 0; ee < 8; ++ee) {
        int e = (ee + cc) & 7;
        Vt[(cc * 8 + e) * 72 + rr] = vv[e];
      }
    }
    __syncthreads();

    // S = Q K^T
    f32x4 s[2][4];
#pragma unroll
    for (int mt = 0; mt < 2; ++mt)
#pragma unroll
      for (int nt = 0; nt < 4; ++nt) s[mt][nt] = (f32x4){0.f, 0.f, 0.f, 0.f};
#pragma unroll
    for (int nt = 0; nt < 4; ++nt) {
      bf16x8 kf[4];
#pragma unroll
      for (int kq = 0; kq < 4; ++kq)
        kf[kq] = *(const bf16x8*)(Kl + (nt * 16 + lr) * 136 + kq * 32 + lq * 8);
#pragma unroll
      for (int kq = 0; kq < 4; ++kq) {
        s[0][nt] = __builtin_amdgcn_mfma_f32_16x16x32_bf16(qf[0][kq], kf[kq], s[0][nt], 0, 0, 0);
        s[1][nt] = __builtin_amdgcn_mfma_f32_16x16x32_bf16(qf[1][kq], kf[kq], s[1][nt], 0, 0, 0);
      }
    }

#pragma unroll
    for (int mt = 0; mt < 2; ++mt) {
#pragma unroll
      for (int r = 0; r < 4; ++r) {
        float mx = fmaxf(fmaxf(s[mt][0][r], s[mt][1][r]), fmaxf(s[mt][2][r], s[mt][3][r]));
        mx = fmaxf(mx, __shfl_xor(mx, 1));
        mx = fmaxf(mx, __shfl_xor(mx, 2));
        mx = fmaxf(mx, __shfl_xor(mx, 4));
        mx = fmaxf(mx, __shfl_xor(mx, 8));
        float mold = mrun[mt][r];
        float mnew = fmaxf(mold, mx);
        float corr = __expf(mold - mnew);
        mrun[mt][r] = mnew;
        float rs = 0.f;
#pragma unroll
        for (int nt = 0; nt < 4; ++nt) {
          float p = __expf(s[mt][nt][r] - mnew);
          s[mt][nt][r] = p;
          rs += p;
        }
        rs += __shfl_xor(rs, 1);
        rs += __shfl_xor(rs, 2);
        rs += __shfl_xor(rs, 4);
        rs += __shfl_xor(rs, 8);
        lrun[mt][r] = lrun[mt][r] * corr + rs;
#pragma unroll
        for (int dt = 0; dt < 8; ++dt) oacc[mt][dt][r] *= corr;
#pragma unroll
        for (int nt = 0; nt < 4; ++nt)
          Pl[wv][(lq * 4 + r) * 72 + nt * 16 + lr] = (bf16)s[mt][nt][r];
      }
      asm volatile("s_waitcnt lgkmcnt(0)" ::: "memory");
#pragma unroll
      for (int kq = 0; kq < 2; ++kq) {
        bf16x8 pf = *(const bf16x8*)(Pl[wv] + lr * 72 + kq * 32 + lq * 8);
#pragma unroll
        for (int dt = 0; dt < 8; ++dt) {
          bf16x8 vf = *(const bf16x8*)(Vt + (dt * 16 + lr) * 72 + kq * 32 + lq * 8);
          oacc[mt][dt] = __builtin_amdgcn_mfma_f32_16x16x32_bf16(pf, vf, oacc[mt][dt], 0, 0, 0);
        }
      }
    }
  }

#pragma unroll
  for (int mt = 0; mt < 2; ++mt) {
#pragma unroll
    for (int r = 0; r < 4; ++r) {
      float inv = 1.f / lrun[mt][r];
#pragma unroll
      for (int dt = 0; dt < 8; ++dt) {
        int trow = qrow0 + mt * 16 + lq * 4 + r;
        base[(size_t)trow * 3840 + dt * 16 + lr] = (bf16)(oacc[mt][dt][r] * inv);
      }
    }
  }
}

extern "C" void kernel_launch(void* const* d_in, const int* in_sizes, int n_in,
                              void* d_out, int out_size, void* d_ws, size_t ws_size,
                              hipStream_t stream) {
  const float* x      = (const float*)d_in[0];
  const float* w_qkv  = (const float*)d_in[1];
  const float* b_qkv  = (const float*)d_in[2];
  const float* w_proj = (const float*)d_in[3];
  const float* b_proj = (const float*)d_in[4];

  // Transients in d_out (dead before final GEMM rewrites it):
  char* outc = (char*)d_out;
  bf16* win   = (bf16*)outc;                          // 32768x1280 bf16
  bf16* wqkvT = (bf16*)(outc + 83886080);             // 3840x1280 bf16
  float* tab  = (float*)(outc + 83886080 + 9830400);  // 256x64x2 f32
  // Workspace:
  char* wsc = (char*)d_ws;
  bf16* qkv    = (bf16*)wsc;                          // 32768x3840 bf16
  bf16* wprojT = (bf16*)(wsc + 251658240);            // 1280x1280 bf16

  k_pack_win<<<20480, 256, 0, stream>>>(x, win);
  k_transpose_w<<<dim3(120, 40), 256, 0, stream>>>(w_qkv, wqkvT, 1280, 3840);
  k_transpose_w<<<dim3(40, 40), 256, 0, stream>>>(w_proj, wprojT, 1280, 1280);
  k_rope_table<<<64, 256, 0, stream>>>(tab);
  k_gemm<0><<<1920, 512, 0, stream>>>(win, 1280, wqkvT, b_qkv, (void*)qkv, 3840);
  k_attn<<<1280, 512, 0, stream>>>(qkv, tab);  // fused RoPE; writes O over q-section
  k_gemm<1><<<640, 512, 0, stream>>>(qkv, 3840, wprojT, b_proj, d_out, 1280);
}

// Round 4
// 792.417 us; speedup vs baseline: 1.0448x; 1.0442x over previous
//
#include <hip/hip_runtime.h>

typedef __bf16 bf16;
typedef __bf16 bf16x8 __attribute__((ext_vector_type(8)));
typedef float f32x4 __attribute__((ext_vector_type(4)));

#define AS1(p) ((const __attribute__((address_space(1))) void*)(p))
#define AS3(p) ((__attribute__((address_space(3))) void*)(p))

// ---------------- pack & window-permute x (fp32) -> win (bf16) ----------------
__global__ void k_pack_win(const float* __restrict__ x, bf16* __restrict__ win) {
  int idx = blockIdx.x * 256 + threadIdx.x;  // one thread = 8 elems
  int r = idx / 160;
  int c8 = idx - r * 160;
  int w = r >> 8, n = r & 255;
  int b = w >> 6, hb = (w >> 3) & 7, wb = w & 7;
  int t = n >> 6, i = (n >> 3) & 7, j = n & 7;
  size_t srow = (size_t)((b * 4 + t) * 4096 + (hb * 8 + i) * 64 + wb * 8 + j);
  const float4* s = (const float4*)(x + srow * 1280 + c8 * 8);
  float4 f0 = s[0], f1 = s[1];
  bf16x8 o;
  o[0] = (bf16)f0.x; o[1] = (bf16)f0.y; o[2] = (bf16)f0.z; o[3] = (bf16)f0.w;
  o[4] = (bf16)f1.x; o[5] = (bf16)f1.y; o[6] = (bf16)f1.z; o[7] = (bf16)f1.w;
  *(bf16x8*)(win + (size_t)idx * 8) = o;
}

// ---------------- transpose + convert weights: (K,N) f32 -> (N,K) bf16 ----------------
__global__ void k_transpose_w(const float* __restrict__ w, bf16* __restrict__ wt,
                              int K, int N) {
  __shared__ float tile[32][33];
  int tx = threadIdx.x & 31, ty = threadIdx.x >> 5;
  int c0 = blockIdx.x * 32, r0 = blockIdx.y * 32;
#pragma unroll
  for (int yy = ty; yy < 32; yy += 8)
    tile[yy][tx] = w[(size_t)(r0 + yy) * N + c0 + tx];
  __syncthreads();
#pragma unroll
  for (int yy = ty; yy < 32; yy += 8)
    wt[(size_t)(c0 + yy) * K + r0 + tx] = (bf16)tile[tx][yy];
}

// ---------------- MRoPE cos/sin table: [n=256][c=64] interleaved (cos,sin) ----------------
__global__ void k_rope_table(float* __restrict__ tab) {
  int idx = blockIdx.x * 256 + threadIdx.x;  // 16384
  int n = idx >> 6, c = idx & 63;
  int t = n >> 6, i = (n >> 3) & 7, j = n & 7;
  float pos = (c < 16) ? (float)t : ((c < 40) ? (float)i : (float)j);
  float inv = powf(10000.f, -(float)c * (1.f / 64.f));
  float a = pos * inv;
  tab[idx * 2] = cosf(a);
  tab[idx * 2 + 1] = sinf(a);
}

// ---------------- GEMM: 256x256 tile, BK=64, 8-wave, 4-phase counted-vmcnt ----------------
// C = A(M,1280; stride lda) * Bt(N,1280)^T + bias.
// EPI 0: bf16 out (stride ldc). EPI 1: f32 out with reverse-window row permute (NT store).
// R4: sched_barrier(0) fences after every inline-asm wait (rule #18 / m201 pattern).
template <int EPI>
__global__ __launch_bounds__(512, 2) void k_gemm(
    const bf16* __restrict__ A, int lda, const bf16* __restrict__ Bt,
    const float* __restrict__ bias, void* __restrict__ Cout, int ldc) {
  __shared__ bf16 sA[2][16384];  // [buf][256 rows][64 k] swizzled
  __shared__ bf16 sB[2][16384];
  const int tid = threadIdx.x, lane = tid & 63, wv = tid >> 6;
  const int wm = wv >> 2, wn = wv & 3;         // 2M x 4N waves, 128x64 per wave
  const int lq = lane >> 4, lr = lane & 15;

  // XCD swizzle: block i runs on XCD i%8; give each XCD 16 contiguous m-blocks x all n.
  int wg_local = blockIdx.x >> 3;
  int xcd = blockIdx.x & 7;
  int n_blk = wg_local >> 4;
  int m_blk = (xcd << 4) + (wg_local & 15);
  const int m0 = m_blk * 256, n0 = n_blk * 256;

  const bf16* Ab = A + (size_t)m0 * lda;
  const bf16* Bb = Bt + (size_t)n0 * 1280;
  const int srow = tid >> 3;                // 0..63 staging row within 64-row round
  const int skg = (tid & 7) ^ (srow & 7);   // swizzled k-group (involution with read XOR)
  const int sldso = wv * 512;               // per-wave elems within an 8KB round

#define WAIT_LGKM0()                                                            \
  do {                                                                          \
    asm volatile("s_waitcnt lgkmcnt(0)" ::: "memory");                          \
    __builtin_amdgcn_sched_barrier(0);                                          \
  } while (0)

#define WAIT_VM(N)                                                              \
  do {                                                                          \
    asm volatile("s_waitcnt vmcnt(" #N ")" ::: "memory");                       \
    __builtin_amdgcn_sched_barrier(0);                                          \
  } while (0)

#define STAGE_A(bufidx, h, kt)                                                  \
  do {                                                                          \
    __builtin_amdgcn_global_load_lds(                                           \
        AS1(Ab + (size_t)((h)*128 + srow) * lda + (kt)*64 + skg * 8),           \
        AS3(&sA[bufidx][(h)*8192 + sldso]), 16, 0, 0);                          \
    __builtin_amdgcn_global_load_lds(                                           \
        AS1(Ab + (size_t)((h)*128 + 64 + srow) * lda + (kt)*64 + skg * 8),      \
        AS3(&sA[bufidx][(h)*8192 + 4096 + sldso]), 16, 0, 0);                   \
  } while (0)

#define STAGE_B(bufidx, h, kt)                                                  \
  do {                                                                          \
    __builtin_amdgcn_global_load_lds(                                           \
        AS1(Bb + (size_t)((h)*128 + srow) * 1280 + (kt)*64 + skg * 8),          \
        AS3(&sB[bufidx][(h)*8192 + sldso]), 16, 0, 0);                          \
    __builtin_amdgcn_global_load_lds(                                           \
        AS1(Bb + (size_t)((h)*128 + 64 + srow) * 1280 + (kt)*64 + skg * 8),     \
        AS3(&sB[bufidx][(h)*8192 + 4096 + sldso]), 16, 0, 0);                   \
  } while (0)

#define LOAD_A(mh)                                                              \
  _Pragma("unroll") for (int mt = 0; mt < 4; ++mt)                              \
  _Pragma("unroll") for (int kb = 0; kb < 2; ++kb) {                            \
    int row_ = wm * 128 + (mh)*64 + mt * 16 + lr;                               \
    int ksw_ = (kb * 32 + lq * 8) ^ ((lr & 7) << 3);                            \
    af[mt][kb] = *(const bf16x8*)&pA[row_ * 64 + ksw_];                         \
  }

#define LOAD_B(dst, nh)                                                         \
  _Pragma("unroll") for (int nt = 0; nt < 2; ++nt)                              \
  _Pragma("unroll") for (int kb = 0; kb < 2; ++kb) {                            \
    int row_ = wn * 64 + (nh)*32 + nt * 16 + lr;                                \
    int ksw_ = (kb * 32 + lq * 8) ^ ((lr & 7) << 3);                            \
    dst[nt][kb] = *(const bf16x8*)&pB[row_ * 64 + ksw_];                        \
  }

#define MFMA_Q(MH, NH, bvec)                                                    \
  _Pragma("unroll") for (int mt = 0; mt < 4; ++mt)                              \
  _Pragma("unroll") for (int nt = 0; nt < 2; ++nt)                              \
  _Pragma("unroll") for (int kb = 0; kb < 2; ++kb)                              \
    acc[(MH)*4 + mt][(NH)*2 + nt] = __builtin_amdgcn_mfma_f32_16x16x32_bf16(    \
        af[mt][kb], bvec[nt][kb], acc[(MH)*4 + mt][(NH)*2 + nt], 0, 0, 0);

  f32x4 acc[8][4];
#pragma unroll
  for (int i = 0; i < 8; ++i)
#pragma unroll
    for (int j = 0; j < 4; ++j) acc[i][j] = (f32x4){0.f, 0.f, 0.f, 0.f};

  // Prologue: tile0 A+B, tile1 B; keep tile1-B in flight past the wait.
  STAGE_A(0, 0, 0); STAGE_A(0, 1, 0);
  STAGE_B(0, 0, 0); STAGE_B(0, 1, 0);
  STAGE_B(1, 0, 1); STAGE_B(1, 1, 1);
  WAIT_VM(4);
  __builtin_amdgcn_s_barrier();

  bf16x8 af[4][2], bfa[2][2], bfb[2][2];

#pragma unroll 2
  for (int t = 0; t < 20; ++t) {
    const int b = t & 1, bn = b ^ 1;
    const int ktA = (t + 1 < 20) ? t + 1 : 19;  // clamp: keeps vmcnt counts uniform
    const int ktB = (t + 2 < 20) ? t + 2 : 19;
    const bf16* pA = sA[b];
    const bf16* pB = sB[b];
    // phase 0: read A(mh0)+B(nh0); stage A-half0 of tile t+1
    LOAD_A(0);
    LOAD_B(bfa, 0);
    STAGE_A(bn, 0, ktA);
    asm volatile("s_waitcnt lgkmcnt(8)" ::: "memory");  // early-drain hint (12 reads issued)
    __builtin_amdgcn_sched_barrier(0);
    __builtin_amdgcn_s_barrier();
    WAIT_LGKM0();
    __builtin_amdgcn_s_setprio(1);
    MFMA_Q(0, 0, bfa);
    __builtin_amdgcn_s_setprio(0);
    __builtin_amdgcn_sched_barrier(0);
    __builtin_amdgcn_s_barrier();
    // phase 1: read B(nh1); stage A-half1 of tile t+1
    LOAD_B(bfb, 1);
    STAGE_A(bn, 1, ktA);
    __builtin_amdgcn_s_barrier();
    WAIT_LGKM0();
    __builtin_amdgcn_s_setprio(1);
    MFMA_Q(0, 1, bfb);
    __builtin_amdgcn_s_setprio(0);
    __builtin_amdgcn_sched_barrier(0);
    __builtin_amdgcn_s_barrier();
    // phase 2: read A(mh1); stage B-half0 of tile t+2 (region retired after ph1)
    LOAD_A(1);
    STAGE_B(b, 0, ktB);
    __builtin_amdgcn_s_barrier();
    WAIT_LGKM0();
    __builtin_amdgcn_s_setprio(1);
    MFMA_Q(1, 0, bfa);
    __builtin_amdgcn_s_setprio(0);
    __builtin_amdgcn_sched_barrier(0);
    __builtin_amdgcn_s_barrier();
    // phase 3: stage B-half1 of tile t+2; counted vmcnt(4) then tile boundary
    STAGE_B(b, 1, ktB);
    __builtin_amdgcn_s_barrier();
    WAIT_LGKM0();
    __builtin_amdgcn_s_setprio(1);
    MFMA_Q(1, 1, bfb);
    __builtin_amdgcn_s_setprio(0);
    WAIT_VM(4);
    __builtin_amdgcn_s_barrier();
  }

#pragma unroll
  for (int ni = 0; ni < 4; ++ni) {
    int col = n0 + wn * 64 + ni * 16 + lr;
    float bv = bias[col];
#pragma unroll
    for (int mi = 0; mi < 8; ++mi) {
#pragma unroll
      for (int r = 0; r < 4; ++r) {
        int row = m0 + wm * 128 + mi * 16 + lq * 4 + r;
        float v = acc[mi][ni][r] + bv;
        if constexpr (EPI == 0) {
          ((bf16*)Cout)[(size_t)row * ldc + col] = (bf16)v;
        } else {
          int w = row >> 8, n = row & 255;
          int b2 = w >> 6, hb = (w >> 3) & 7, wb = w & 7;
          int t2 = n >> 6, i2 = (n >> 3) & 7, j2 = n & 7;
          size_t orow = (size_t)((b2 * 4 + t2) * 4096 + (hb * 8 + i2) * 64 + wb * 8 + j2);
          __builtin_nontemporal_store(v, &((float*)Cout)[orow * ldc + col]);
        }
      }
    }
  }
#undef STAGE_A
#undef STAGE_B
#undef LOAD_A
#undef LOAD_B
#undef MFMA_Q
#undef WAIT_LGKM0
#undef WAIT_VM
}

// ---------------- attention + fused MRoPE: one block per (window, head) ----------------
// Reads q/k/v from qkv (stride 3840), applies RoPE to Q (with 1/sqrt(d) scale) and K
// on the fly, writes O into the q-section in place.
__global__ __launch_bounds__(512) void k_attn(bf16* __restrict__ qkv,
                                              const float* __restrict__ tab) {
  int wh = blockIdx.x;
  int win = wh / 10, h = wh - win * 10;
  bf16* base = qkv + (size_t)win * 256 * 3840 + h * 128;
  const int tid = threadIdx.x, lane = tid & 63, wv = tid >> 6;
  const int lq = lane >> 4, lr = lane & 15;
  const int qrow0 = wv * 32;

  __shared__ bf16 Kl[64 * 136];    // [tok][d], pad +8
  __shared__ bf16 Vt[128 * 72];    // [d][tok], pad +8
  __shared__ bf16 Pl[8][16 * 72];  // per-wave P strip

  // Q fragments + in-register RoPE + scale
  bf16x8 qf[2][4];
#pragma unroll
  for (int mt = 0; mt < 2; ++mt) {
    int n = qrow0 + mt * 16 + lr;
#pragma unroll
    for (int kq = 0; kq < 4; ++kq)
      qf[mt][kq] = *(const bf16x8*)(base + (size_t)n * 3840 + kq * 32 + lq * 8);
    const float* tb = tab + (n * 64 + lq * 8) * 2;
#pragma unroll
    for (int kq = 0; kq < 2; ++kq)
#pragma unroll
      for (int e = 0; e < 8; ++e) {
        float cs = tb[(kq * 32 + e) * 2], sn = tb[(kq * 32 + e) * 2 + 1];
        float lo = (float)qf[mt][kq][e], hi = (float)qf[mt][kq + 2][e];
        qf[mt][kq][e] = (bf16)((lo * cs - hi * sn) * 0.08838834764831845f);
        qf[mt][kq + 2][e] = (bf16)((hi * cs + lo * sn) * 0.08838834764831845f);
      }
  }

  float mrun[2][4], lrun[2][4];
  f32x4 oacc[2][8];
#pragma unroll
  for (int mt = 0; mt < 2; ++mt)
#pragma unroll
    for (int r = 0; r < 4; ++r) { mrun[mt][r] = -1e30f; lrun[mt][r] = 0.f; }
#pragma unroll
  for (int mt = 0; mt < 2; ++mt)
#pragma unroll
    for (int dt = 0; dt < 8; ++dt) oacc[mt][dt] = (f32x4){0.f, 0.f, 0.f, 0.f};

  for (int kb_t = 0; kb_t < 4; ++kb_t) {
    __syncthreads();
    // stage K block [64][128] with fused RoPE: 512 items (row, col-pair)
    {
      int rr = tid >> 3, cp = tid & 7;
      const bf16* krow = base + 1280 + (size_t)(kb_t * 64 + rr) * 3840;
      bf16x8 klo = *(const bf16x8*)(krow + cp * 8);
      bf16x8 khi = *(const bf16x8*)(krow + cp * 8 + 64);
      const float* tb = tab + ((kb_t * 64 + rr) * 64 + cp * 8) * 2;
      bf16x8 olo, ohi;
#pragma unroll
      for (int e = 0; e < 8; ++e) {
        float cs = tb[e * 2], sn = tb[e * 2 + 1];
        float lo = (float)klo[e], hi = (float)khi[e];
        olo[e] = (bf16)(lo * cs - hi * sn);
        ohi[e] = (bf16)(hi * cs + lo * sn);
      }
      *(bf16x8*)(Kl + rr * 136 + cp * 8) = olo;
      *(bf16x8*)(Kl + rr * 136 + cp * 8 + 64) = ohi;
    }
    // stage V^T block [128][64]
#pragma unroll
    for (int p = 0; p < 2; ++p) {
      int item = p * 512 + tid;
      int rr = item >> 4, cc = item & 15;
      bf16x8 vv = *(const bf16x8*)(base + 2560 + (size_t)(kb_t * 64 + rr) * 3840 + cc * 8);
#pragma unroll
      for (int ee = 0; ee < 8; ++ee) {
        int e = (ee + cc) & 7;
        Vt[(cc * 8 + e) * 72 + rr] = vv[e];
      }
    }
    __syncthreads();

    // S = Q K^T
    f32x4 s[2][4];
#pragma unroll
    for (int mt = 0; mt < 2; ++mt)
#pragma unroll
      for (int nt = 0; nt < 4; ++nt) s[mt][nt] = (f32x4){0.f, 0.f, 0.f, 0.f};
#pragma unroll
    for (int nt = 0; nt < 4; ++nt) {
      bf16x8 kf[4];
#pragma unroll
      for (int kq = 0; kq < 4; ++kq)
        kf[kq] = *(const bf16x8*)(Kl + (nt * 16 + lr) * 136 + kq * 32 + lq * 8);
#pragma unroll
      for (int kq = 0; kq < 4; ++kq) {
        s[0][nt] = __builtin_amdgcn_mfma_f32_16x16x32_bf16(qf[0][kq], kf[kq], s[0][nt], 0, 0, 0);
        s[1][nt] = __builtin_amdgcn_mfma_f32_16x16x32_bf16(qf[1][kq], kf[kq], s[1][nt], 0, 0, 0);
      }
    }

#pragma unroll
    for (int mt = 0; mt < 2; ++mt) {
#pragma unroll
      for (int r = 0; r < 4; ++r) {
        float mx = fmaxf(fmaxf(s[mt][0][r], s[mt][1][r]), fmaxf(s[mt][2][r], s[mt][3][r]));
        mx = fmaxf(mx, __shfl_xor(mx, 1));
        mx = fmaxf(mx, __shfl_xor(mx, 2));
        mx = fmaxf(mx, __shfl_xor(mx, 4));
        mx = fmaxf(mx, __shfl_xor(mx, 8));
        float mold = mrun[mt][r];
        float mnew = fmaxf(mold, mx);
        float corr = __expf(mold - mnew);
        mrun[mt][r] = mnew;
        float rs = 0.f;
#pragma unroll
        for (int nt = 0; nt < 4; ++nt) {
          float p = __expf(s[mt][nt][r] - mnew);
          s[mt][nt][r] = p;
          rs += p;
        }
        rs += __shfl_xor(rs, 1);
        rs += __shfl_xor(rs, 2);
        rs += __shfl_xor(rs, 4);
        rs += __shfl_xor(rs, 8);
        lrun[mt][r] = lrun[mt][r] * corr + rs;
#pragma unroll
        for (int dt = 0; dt < 8; ++dt) oacc[mt][dt][r] *= corr;
#pragma unroll
        for (int nt = 0; nt < 4; ++nt)
          Pl[wv][(lq * 4 + r) * 72 + nt * 16 + lr] = (bf16)s[mt][nt][r];
      }
      asm volatile("s_waitcnt lgkmcnt(0)" ::: "memory");
      __builtin_amdgcn_sched_barrier(0);
#pragma unroll
      for (int kq = 0; kq < 2; ++kq) {
        bf16x8 pf = *(const bf16x8*)(Pl[wv] + lr * 72 + kq * 32 + lq * 8);
#pragma unroll
        for (int dt = 0; dt < 8; ++dt) {
          bf16x8 vf = *(const bf16x8*)(Vt + (dt * 16 + lr) * 72 + kq * 32 + lq * 8);
          oacc[mt][dt] = __builtin_amdgcn_mfma_f32_16x16x32_bf16(pf, vf, oacc[mt][dt], 0, 0, 0);
        }
      }
    }
  }

#pragma unroll
  for (int mt = 0; mt < 2; ++mt) {
#pragma unroll
    for (int r = 0; r < 4; ++r) {
      float inv = 1.f / lrun[mt][r];
#pragma unroll
      for (int dt = 0; dt < 8; ++dt) {
        int trow = qrow0 + mt * 16 + lq * 4 + r;
        base[(size_t)trow * 3840 + dt * 16 + lr] = (bf16)(oacc[mt][dt][r] * inv);
      }
    }
  }
}

extern "C" void kernel_launch(void* const* d_in, const int* in_sizes, int n_in,
                              void* d_out, int out_size, void* d_ws, size_t ws_size,
                              hipStream_t stream) {
  const float* x      = (const float*)d_in[0];
  const float* w_qkv  = (const float*)d_in[1];
  const float* b_qkv  = (const float*)d_in[2];
  const float* w_proj = (const float*)d_in[3];
  const float* b_proj = (const float*)d_in[4];

  // Transients in d_out (dead before final GEMM rewrites it):
  char* outc = (char*)d_out;
  bf16* win   = (bf16*)outc;                          // 32768x1280 bf16
  bf16* wqkvT = (bf16*)(outc + 83886080);             // 3840x1280 bf16
  float* tab  = (float*)(outc + 83886080 + 9830400);  // 256x64x2 f32
  // Workspace:
  char* wsc = (char*)d_ws;
  bf16* qkv    = (bf16*)wsc;                          // 32768x3840 bf16
  bf16* wprojT = (bf16*)(wsc + 251658240);            // 1280x1280 bf16

  k_pack_win<<<20480, 256, 0, stream>>>(x, win);
  k_transpose_w<<<dim3(120, 40), 256, 0, stream>>>(w_qkv, wqkvT, 1280, 3840);
  k_transpose_w<<<dim3(40, 40), 256, 0, stream>>>(w_proj, wprojT, 1280, 1280);
  k_rope_table<<<64, 256, 0, stream>>>(tab);
  k_gemm<0><<<1920, 512, 0, stream>>>(win, 1280, wqkvT, b_qkv, (void*)qkv, 3840);
  k_attn<<<1280, 512, 0, stream>>>(qkv, tab);  // fused RoPE; writes O over q-section
  k_gemm<1><<<640, 512, 0, stream>>>(qkv, 3840, wprojT, b_proj, d_out, 1280);
}